// Round 1
// baseline (57.864 us; speedup 1.0000x reference)
//
#include <hip/hip_runtime.h>

#define BS 16
#define NP 500000
#define NOBJ 16
#define NSEG3 (NOBJ * 3)

// ws layout (unsigned words):
//   [0, 768)      gmin keys  (BS*NOBJ*3)
//   [768, 1536)   gmax keys
//   [1536, 1792)  gpres      (BS*NOBJ)
//   [1792, 2048)  granks     (int: final global segment id per (b, original tag))

// Order-preserving float -> uint key (min/max over keys == min/max over floats)
__device__ __forceinline__ unsigned fkey(float f) {
    unsigned u = __float_as_uint(f);
    return (u & 0x80000000u) ? ~u : (u | 0x80000000u);
}
__device__ __forceinline__ float keyf(unsigned k) {
    unsigned u = (k & 0x80000000u) ? (k ^ 0x80000000u) : ~k;
    return __uint_as_float(u);
}

__global__ void kinit(unsigned* ws) {
    int i = blockIdx.x * blockDim.x + threadIdx.x;
    if (i < 2048) ws[i] = (i < 768) ? 0xFFFFFFFFu : 0u;
}

__global__ __launch_bounds__(256) void kreduce(const float* __restrict__ pc,
                                               const int* __restrict__ tag,
                                               unsigned* __restrict__ ws) {
    __shared__ unsigned lmin[NSEG3], lmax[NSEG3];
    const int b = blockIdx.y;
    const int tid = threadIdx.x;
    if (tid < NSEG3) { lmin[tid] = 0xFFFFFFFFu; lmax[tid] = 0u; }
    __syncthreads();

    const int4*   tag4 = (const int4*)(tag + (size_t)b * NP);
    const float4* pc4  = (const float4*)(pc + (size_t)b * NP * 3);
    const int nv = NP / 4;  // 125000, exact
    const int stride = gridDim.x * blockDim.x;
    for (int i = blockIdx.x * blockDim.x + tid; i < nv; i += stride) {
        int4 t = tag4[i];
        float4 f0 = pc4[i * 3 + 0];  // x0 y0 z0 x1
        float4 f1 = pc4[i * 3 + 1];  // y1 z1 x2 y2
        float4 f2 = pc4[i * 3 + 2];  // z2 x3 y3 z3
        int a0 = t.x * 3, a1 = t.y * 3, a2 = t.z * 3, a3 = t.w * 3;
        unsigned k;
        k = fkey(f0.x); atomicMin(&lmin[a0 + 0], k); atomicMax(&lmax[a0 + 0], k);
        k = fkey(f0.y); atomicMin(&lmin[a0 + 1], k); atomicMax(&lmax[a0 + 1], k);
        k = fkey(f0.z); atomicMin(&lmin[a0 + 2], k); atomicMax(&lmax[a0 + 2], k);
        k = fkey(f0.w); atomicMin(&lmin[a1 + 0], k); atomicMax(&lmax[a1 + 0], k);
        k = fkey(f1.x); atomicMin(&lmin[a1 + 1], k); atomicMax(&lmax[a1 + 1], k);
        k = fkey(f1.y); atomicMin(&lmin[a1 + 2], k); atomicMax(&lmax[a1 + 2], k);
        k = fkey(f1.z); atomicMin(&lmin[a2 + 0], k); atomicMax(&lmax[a2 + 0], k);
        k = fkey(f1.w); atomicMin(&lmin[a2 + 1], k); atomicMax(&lmax[a2 + 1], k);
        k = fkey(f2.x); atomicMin(&lmin[a2 + 2], k); atomicMax(&lmax[a2 + 2], k);
        k = fkey(f2.y); atomicMin(&lmin[a3 + 0], k); atomicMax(&lmax[a3 + 0], k);
        k = fkey(f2.z); atomicMin(&lmin[a3 + 1], k); atomicMax(&lmax[a3 + 1], k);
        k = fkey(f2.w); atomicMin(&lmin[a3 + 2], k); atomicMax(&lmax[a3 + 2], k);
    }
    __syncthreads();

    unsigned* gmin  = ws;
    unsigned* gmax  = ws + 768;
    unsigned* gpres = ws + 1536;
    if (tid < NSEG3) {
        atomicMin(&gmin[b * NSEG3 + tid], lmin[tid]);
        atomicMax(&gmax[b * NSEG3 + tid], lmax[tid]);
    }
    if (tid < NOBJ) {
        // any point with this tag updated lmin or lmax away from its sentinel
        if (lmin[tid * 3] != 0xFFFFFFFFu || lmax[tid * 3] != 0u)
            atomicOr(&gpres[b * NOBJ + tid], 1u);
    }
}

__global__ void kfinal(unsigned* ws, float* __restrict__ out) {
    int b = threadIdx.x;
    if (b >= BS) return;
    const unsigned* gmin  = ws;
    const unsigned* gmax  = ws + 768;
    const unsigned* gpres = ws + 1536;
    int* granks = (int*)(ws + 1792);

    int tag_of[NOBJ];
    int r = -1;  // ranks[t] = cumsum(present)[t] - 1
    for (int t = 0; t < NOBJ; ++t) {
        if (gpres[b * NOBJ + t]) { r += 1; tag_of[r] = t; }
        granks[b * NOBJ + t] = r + b * NOBJ;  // global segment id for this tag
    }
    int nd = r + 1;  // number of distinct tags present

    // bbox rows: [min0, max0, min1, max1, ...] over dense ids; empty dense ids -> 0
    float bbox[32][3];
    for (int i = 0; i < NOBJ; ++i) {
        for (int c = 0; c < 3; ++c) {
            float mn = 0.f, mx = 0.f;
            if (i < nd) {
                int t = tag_of[i];
                mn = keyf(gmin[b * NSEG3 + t * 3 + c]);
                mx = keyf(gmax[b * NSEG3 + t * 3 + c]);
            }
            bbox[2 * i][c] = mn;
            bbox[2 * i + 1][c] = mx;
        }
    }
    float* ob = out + (size_t)b * 48 * 3;
    for (int j = 0; j < 32; ++j)
        for (int c = 0; c < 3; ++c)
            ob[j * 3 + c] = bbox[j][c];
    // faithful torch barycenter: row-major split of the interleaved bbox rows
    for (int j = 0; j < 16; ++j)
        for (int c = 0; c < 3; ++c)
            ob[(32 + j) * 3 + c] = 0.5f * (bbox[j][c] + bbox[16 + j][c]);
}

__global__ __launch_bounds__(256) void krelabel(const int* __restrict__ tag,
                                                const unsigned* __restrict__ ws,
                                                float* __restrict__ out) {
    __shared__ float lr[NOBJ];
    const int b = blockIdx.y;
    if (threadIdx.x < NOBJ) {
        const int* granks = (const int*)(ws + 1792);
        lr[threadIdx.x] = (float)granks[b * NOBJ + threadIdx.x];
    }
    __syncthreads();

    const int4* tag4 = (const int4*)(tag + (size_t)b * NP);
    float4* out4 = (float4*)(out + 2304 + (size_t)b * NP);  // 2304 floats = keypoints
    const int nv = NP / 4;
    const int stride = gridDim.x * blockDim.x;
    for (int i = blockIdx.x * blockDim.x + threadIdx.x; i < nv; i += stride) {
        int4 t = tag4[i];
        out4[i] = make_float4(lr[t.x], lr[t.y], lr[t.z], lr[t.w]);
    }
}

extern "C" void kernel_launch(void* const* d_in, const int* in_sizes, int n_in,
                              void* d_out, int out_size, void* d_ws, size_t ws_size,
                              hipStream_t stream) {
    const float* pc  = (const float*)d_in[0];
    const int*   tag = (const int*)d_in[1];
    float* out = (float*)d_out;
    unsigned* ws = (unsigned*)d_ws;

    kinit<<<8, 256, 0, stream>>>(ws);
    kreduce<<<dim3(64, BS), 256, 0, stream>>>(pc, tag, ws);
    kfinal<<<1, 64, 0, stream>>>(ws, out);
    krelabel<<<dim3(128, BS), 256, 0, stream>>>(tag, ws, out);
}

// Round 2
// 53.624 us; speedup vs baseline: 1.0791x; 1.0791x over previous
//
#include <hip/hip_runtime.h>

#define BS 16
#define NP 500000
#define NOBJ 16
#define NSEG3 48        // NOBJ*3
#define GX1 64          // blocks per scene, K1 (presence prepass)
#define GX2 128         // blocks per scene, K2 (main fused pass)

// ws layout (unsigned words):
//   [0, 768)      gmin keys   (BS*NSEG3)   sentinel 0xFFFFFFFF, set by K1 x==0
//   [768, 1536)   gmax keys   (BS*NSEG3)   sentinel 0
//   [1536, 2560)  pres_slots  (BS*GX1)     per-block presence bitmask (K1 writes all)
//   [2560, 2576)  gmask       (BS)         combined mask (K2 x==0 writes, K3 reads)

// Order-preserving float -> uint key (min/max over keys == min/max over floats)
__device__ __forceinline__ unsigned fkey(float f) {
    unsigned u = __float_as_uint(f);
    return (u & 0x80000000u) ? ~u : (u | 0x80000000u);
}
__device__ __forceinline__ float keyf(unsigned k) {
    unsigned u = (k & 0x80000000u) ? (k ^ 0x80000000u) : ~k;
    return __uint_as_float(u);
}

// K1: presence prepass over tags; also writes min/max sentinels (x==0 blocks).
__global__ __launch_bounds__(256) void k1_presence(const int* __restrict__ tag,
                                                   unsigned* __restrict__ ws) {
    __shared__ unsigned lmask;
    const int b = blockIdx.y, x = blockIdx.x, tid = threadIdx.x;
    if (tid == 0) lmask = 0u;
    if (x == 0 && tid < NSEG3) {
        ws[b * NSEG3 + tid] = 0xFFFFFFFFu;   // gmin sentinel
        ws[768 + b * NSEG3 + tid] = 0u;      // gmax sentinel
    }
    __syncthreads();

    const int4* tag4 = (const int4*)(tag + (size_t)b * NP);
    unsigned m = 0u;
    const int stride = GX1 * 256;
    for (int i = x * 256 + tid; i < NP / 4; i += stride) {
        int4 t = tag4[i];
        m |= (1u << t.x) | (1u << t.y) | (1u << t.z) | (1u << t.w);
    }
    atomicOr(&lmask, m);
    __syncthreads();
    if (tid == 0) ws[1536 + b * GX1 + x] = lmask;
}

// K2: fused bbox-reduce + obj_batch write. Reads pc+tag once, writes obj_batch.
__global__ __launch_bounds__(256) void k2_main(const float* __restrict__ pc,
                                               const int* __restrict__ tag,
                                               unsigned* __restrict__ ws,
                                               float* __restrict__ out) {
    __shared__ unsigned lmin[4 * NSEG3], lmax[4 * NSEG3];
    __shared__ unsigned lmask;
    __shared__ float lut[NOBJ];
    const int b = blockIdx.y, x = blockIdx.x, tid = threadIdx.x;

    if (tid == 0) lmask = 0u;
    if (tid < 4 * NSEG3) { lmin[tid] = 0xFFFFFFFFu; lmax[tid] = 0u; }
    __syncthreads();
    if (tid < GX1) atomicOr(&lmask, ws[1536 + b * GX1 + tid]);
    __syncthreads();
    const unsigned mask = lmask;
    if (tid < NOBJ)
        lut[tid] = (float)(__popc(mask & ((2u << tid) - 1u)) - 1 + b * NOBJ);
    if (x == 0 && tid == 0) ws[2560 + b] = mask;
    __syncthreads();

    unsigned* wmin = lmin + (tid >> 6) * NSEG3;  // per-wave private table
    unsigned* wmax = lmax + (tid >> 6) * NSEG3;

    const int4*   tag4 = (const int4*)(tag + (size_t)b * NP);
    const float4* pc4  = (const float4*)(pc + (size_t)b * NP * 3);
    float4* out4 = (float4*)(out + 2304 + (size_t)b * NP);  // 2304 floats = keypoints
    const int stride = GX2 * 256;
    for (int i = x * 256 + tid; i < NP / 4; i += stride) {
        int4 t = tag4[i];
        float4 f0 = pc4[i * 3 + 0];  // x0 y0 z0 x1
        float4 f1 = pc4[i * 3 + 1];  // y1 z1 x2 y2
        float4 f2 = pc4[i * 3 + 2];  // z2 x3 y3 z3
        out4[i] = make_float4(lut[t.x], lut[t.y], lut[t.z], lut[t.w]);
        int a0 = t.x * 3, a1 = t.y * 3, a2 = t.z * 3, a3 = t.w * 3;
        unsigned k;
        k = fkey(f0.x); atomicMin(&wmin[a0 + 0], k); atomicMax(&wmax[a0 + 0], k);
        k = fkey(f0.y); atomicMin(&wmin[a0 + 1], k); atomicMax(&wmax[a0 + 1], k);
        k = fkey(f0.z); atomicMin(&wmin[a0 + 2], k); atomicMax(&wmax[a0 + 2], k);
        k = fkey(f0.w); atomicMin(&wmin[a1 + 0], k); atomicMax(&wmax[a1 + 0], k);
        k = fkey(f1.x); atomicMin(&wmin[a1 + 1], k); atomicMax(&wmax[a1 + 1], k);
        k = fkey(f1.y); atomicMin(&wmin[a1 + 2], k); atomicMax(&wmax[a1 + 2], k);
        k = fkey(f1.z); atomicMin(&wmin[a2 + 0], k); atomicMax(&wmax[a2 + 0], k);
        k = fkey(f1.w); atomicMin(&wmin[a2 + 1], k); atomicMax(&wmax[a2 + 1], k);
        k = fkey(f2.x); atomicMin(&wmin[a2 + 2], k); atomicMax(&wmax[a2 + 2], k);
        k = fkey(f2.y); atomicMin(&wmin[a3 + 0], k); atomicMax(&wmax[a3 + 0], k);
        k = fkey(f2.z); atomicMin(&wmin[a3 + 1], k); atomicMax(&wmax[a3 + 1], k);
        k = fkey(f2.w); atomicMin(&wmin[a3 + 2], k); atomicMax(&wmax[a3 + 2], k);
    }
    __syncthreads();

    if (tid < NSEG3) {
        unsigned mn = min(min(lmin[tid], lmin[tid + NSEG3]),
                          min(lmin[tid + 2 * NSEG3], lmin[tid + 3 * NSEG3]));
        unsigned mx = max(max(lmax[tid], lmax[tid + NSEG3]),
                          max(lmax[tid + 2 * NSEG3], lmax[tid + 3 * NSEG3]));
        atomicMin(&ws[b * NSEG3 + tid], mn);
        atomicMax(&ws[768 + b * NSEG3 + tid], mx);
    }
}

// K3: keypoints epilogue (one thread per scene).
__global__ void k3_keypoints(const unsigned* __restrict__ ws, float* __restrict__ out) {
    int b = threadIdx.x;
    if (b >= BS) return;
    const unsigned* gmin = ws;
    const unsigned* gmax = ws + 768;
    unsigned mask = ws[2560 + b];

    int tag_of[NOBJ];
    int r = -1;
    for (int t = 0; t < NOBJ; ++t)
        if ((mask >> t) & 1u) { ++r; tag_of[r] = t; }
    int nd = r + 1;

    // bbox rows: [min0, max0, min1, max1, ...] over dense ids; empty dense ids -> 0
    float bbox[32][3];
    for (int i = 0; i < NOBJ; ++i) {
        for (int c = 0; c < 3; ++c) {
            float mn = 0.f, mx = 0.f;
            if (i < nd) {
                int t = tag_of[i];
                mn = keyf(gmin[b * NSEG3 + t * 3 + c]);
                mx = keyf(gmax[b * NSEG3 + t * 3 + c]);
            }
            bbox[2 * i][c] = mn;
            bbox[2 * i + 1][c] = mx;
        }
    }
    float* ob = out + (size_t)b * 48 * 3;
    for (int j = 0; j < 32; ++j)
        for (int c = 0; c < 3; ++c)
            ob[j * 3 + c] = bbox[j][c];
    // faithful torch barycenter: row-major split of interleaved bbox rows
    for (int j = 0; j < 16; ++j)
        for (int c = 0; c < 3; ++c)
            ob[(32 + j) * 3 + c] = 0.5f * (bbox[j][c] + bbox[16 + j][c]);
}

extern "C" void kernel_launch(void* const* d_in, const int* in_sizes, int n_in,
                              void* d_out, int out_size, void* d_ws, size_t ws_size,
                              hipStream_t stream) {
    const float* pc  = (const float*)d_in[0];
    const int*   tag = (const int*)d_in[1];
    float* out = (float*)d_out;
    unsigned* ws = (unsigned*)d_ws;

    k1_presence<<<dim3(GX1, BS), 256, 0, stream>>>(tag, ws);
    k2_main<<<dim3(GX2, BS), 256, 0, stream>>>(pc, tag, ws, out);
    k3_keypoints<<<1, 64, 0, stream>>>(ws, out);
}

// Round 4
// 41.402 us; speedup vs baseline: 1.3976x; 1.2952x over previous
//
#include <hip/hip_runtime.h>

#define BS 16
#define NP 500000
#define NOBJ 16
#define NSEG3 48        // NOBJ*3
#define GX 128          // blocks per scene, main kernel

typedef float f32x4 __attribute__((ext_vector_type(4)));  // native vec for nontemporal store

// ws word layout (all slots written unconditionally every call -> no init pass):
//   slotmin : [0, BS*GX*48)          = [0, 98304)     per-block min keys
//   slotmax : [98304, 196608)                          per-block max keys
//   slotmask: [196608, 198656)        BS*GX            per-block presence bitmask
#define WS_SMAX 98304
#define WS_SMSK 196608

// Order-preserving float -> uint key (min/max over keys == min/max over floats)
__device__ __forceinline__ unsigned fkey(float f) {
    unsigned u = __float_as_uint(f);
    return (u & 0x80000000u) ? ~u : (u | 0x80000000u);
}
__device__ __forceinline__ float keyf(unsigned k) {
    unsigned u = (k & 0x80000000u) ? (k ^ 0x80000000u) : ~k;
    return __uint_as_float(u);
}

// Main fused pass: read pc+tag once; speculative obj_batch = tag + b*16;
// per-block bbox partials via bank-spread LDS atomics (4 sub-tables by lane&3:
// word index (t*3+c)*4 + sub -> bank (12t+4c+sub)%32 covers all 32 banks, ~2 lanes/bank).
__global__ __launch_bounds__(256) void kmain(const float* __restrict__ pc,
                                             const int* __restrict__ tag,
                                             unsigned* __restrict__ ws,
                                             float* __restrict__ out) {
    __shared__ unsigned lmin[4 * NSEG3], lmax[4 * NSEG3];
    __shared__ unsigned lmask;
    const int b = blockIdx.y, x = blockIdx.x, tid = threadIdx.x;
    if (tid == 0) lmask = 0u;
    if (tid < 4 * NSEG3) { lmin[tid] = 0xFFFFFFFFu; lmax[tid] = 0u; }
    __syncthreads();

    const int sub = tid & 3;
    const float fb = (float)(b * NOBJ);
    const int4*   tag4 = (const int4*)(tag + (size_t)b * NP);
    const float4* pc4  = (const float4*)(pc + (size_t)b * NP * 3);
    f32x4* out4 = (f32x4*)(out + 2304 + (size_t)b * NP);  // 2304 floats = keypoints
    unsigned m = 0u;
    for (int i = x * 256 + tid; i < NP / 4; i += GX * 256) {
        int4 t = tag4[i];
        float4 f0 = pc4[i * 3 + 0];  // x0 y0 z0 x1
        float4 f1 = pc4[i * 3 + 1];  // y1 z1 x2 y2
        float4 f2 = pc4[i * 3 + 2];  // z2 x3 y3 z3
        f32x4 ob = {fb + (float)t.x, fb + (float)t.y, fb + (float)t.z, fb + (float)t.w};
        __builtin_nontemporal_store(ob, &out4[i]);
        m |= (1u << t.x) | (1u << t.y) | (1u << t.z) | (1u << t.w);
        int a0 = t.x * 12 + sub, a1 = t.y * 12 + sub, a2 = t.z * 12 + sub, a3 = t.w * 12 + sub;
        unsigned k;
        k = fkey(f0.x); atomicMin(&lmin[a0 + 0], k); atomicMax(&lmax[a0 + 0], k);
        k = fkey(f0.y); atomicMin(&lmin[a0 + 4], k); atomicMax(&lmax[a0 + 4], k);
        k = fkey(f0.z); atomicMin(&lmin[a0 + 8], k); atomicMax(&lmax[a0 + 8], k);
        k = fkey(f0.w); atomicMin(&lmin[a1 + 0], k); atomicMax(&lmax[a1 + 0], k);
        k = fkey(f1.x); atomicMin(&lmin[a1 + 4], k); atomicMax(&lmax[a1 + 4], k);
        k = fkey(f1.y); atomicMin(&lmin[a1 + 8], k); atomicMax(&lmax[a1 + 8], k);
        k = fkey(f1.z); atomicMin(&lmin[a2 + 0], k); atomicMax(&lmax[a2 + 0], k);
        k = fkey(f1.w); atomicMin(&lmin[a2 + 4], k); atomicMax(&lmax[a2 + 4], k);
        k = fkey(f2.x); atomicMin(&lmin[a2 + 8], k); atomicMax(&lmax[a2 + 8], k);
        k = fkey(f2.y); atomicMin(&lmin[a3 + 0], k); atomicMax(&lmax[a3 + 0], k);
        k = fkey(f2.z); atomicMin(&lmin[a3 + 4], k); atomicMax(&lmax[a3 + 4], k);
        k = fkey(f2.w); atomicMin(&lmin[a3 + 8], k); atomicMax(&lmax[a3 + 8], k);
    }
    atomicOr(&lmask, m);
    __syncthreads();

    const int slot = b * GX + x;
    if (tid < NSEG3) {
        unsigned mn = min(min(lmin[tid * 4 + 0], lmin[tid * 4 + 1]),
                          min(lmin[tid * 4 + 2], lmin[tid * 4 + 3]));
        unsigned mx = max(max(lmax[tid * 4 + 0], lmax[tid * 4 + 1]),
                          max(lmax[tid * 4 + 2], lmax[tid * 4 + 3]));
        ws[slot * NSEG3 + tid] = mn;
        ws[WS_SMAX + slot * NSEG3 + tid] = mx;
    }
    if (tid == 0) ws[WS_SMSK + slot] = lmask;
}

// K3: per-scene reduction of block partials + keypoints epilogue.
// Rare path (some tag absent -> relabel not identity): rewrite scene's obj_batch.
__global__ __launch_bounds__(256) void k3(const unsigned* __restrict__ ws,
                                          float* __restrict__ out) {
    __shared__ unsigned smin[NSEG3], smax[NSEG3];
    __shared__ unsigned smask;
    __shared__ float lut[NOBJ];
    const int b = blockIdx.x, tid = threadIdx.x;

    if (tid < NSEG3) {
        unsigned mn = 0xFFFFFFFFu;
        #pragma unroll 8
        for (int x = 0; x < GX; ++x) mn = min(mn, ws[(b * GX + x) * NSEG3 + tid]);
        smin[tid] = mn;
    } else if (tid >= 64 && tid < 64 + NSEG3) {
        const int e = tid - 64;
        unsigned mx = 0u;
        #pragma unroll 8
        for (int x = 0; x < GX; ++x) mx = max(mx, ws[WS_SMAX + (b * GX + x) * NSEG3 + e]);
        smax[e] = mx;
    } else if (tid == 128) {
        unsigned mm = 0u;
        #pragma unroll 8
        for (int x = 0; x < GX; ++x) mm |= ws[WS_SMSK + b * GX + x];
        smask = mm;
    }
    __syncthreads();
    const unsigned mask = smask;

    if (tid == 0) {
        int tag_of[NOBJ];
        int r = -1;
        for (int t = 0; t < NOBJ; ++t)
            if ((mask >> t) & 1u) { ++r; tag_of[r] = t; }
        int nd = r + 1;
        // bbox rows: [min0, max0, ...] over dense ids; empty dense ids -> 0
        float bbox[32][3];
        for (int i = 0; i < NOBJ; ++i) {
            for (int c = 0; c < 3; ++c) {
                float mn = 0.f, mx = 0.f;
                if (i < nd) {
                    int t = tag_of[i];
                    mn = keyf(smin[t * 3 + c]);
                    mx = keyf(smax[t * 3 + c]);
                }
                bbox[2 * i][c] = mn;
                bbox[2 * i + 1][c] = mx;
            }
        }
        float* ob = out + (size_t)b * 48 * 3;
        for (int j = 0; j < 32; ++j)
            for (int c = 0; c < 3; ++c)
                ob[j * 3 + c] = bbox[j][c];
        // faithful torch barycenter: row-major split of interleaved bbox rows
        for (int j = 0; j < 16; ++j)
            for (int c = 0; c < 3; ++c)
                ob[(32 + j) * 3 + c] = 0.5f * (bbox[j][c] + bbox[16 + j][c]);
    }

    if (mask != 0xFFFFu) {  // rare, input-determined -> deterministic; block-uniform
        if (tid < NOBJ)
            lut[tid] = (float)(__popc(mask & ((2u << tid) - 1u)) - 1 + b * NOBJ);
        __syncthreads();
        const float fb = (float)(b * NOBJ);
        float4* out4 = (float4*)(out + 2304 + (size_t)b * NP);
        for (int i = tid; i < NP / 4; i += 256) {
            float4 v = out4[i];
            out4[i] = make_float4(lut[(int)(v.x - fb)], lut[(int)(v.y - fb)],
                                  lut[(int)(v.z - fb)], lut[(int)(v.w - fb)]);
        }
    }
}

extern "C" void kernel_launch(void* const* d_in, const int* in_sizes, int n_in,
                              void* d_out, int out_size, void* d_ws, size_t ws_size,
                              hipStream_t stream) {
    const float* pc  = (const float*)d_in[0];
    const int*   tag = (const int*)d_in[1];
    float* out = (float*)d_out;
    unsigned* ws = (unsigned*)d_ws;

    kmain<<<dim3(GX, BS), 256, 0, stream>>>(pc, tag, ws, out);
    k3<<<BS, 256, 0, stream>>>(ws, out);
}

// Round 5
// 39.911 us; speedup vs baseline: 1.4498x; 1.0374x over previous
//
#include <hip/hip_runtime.h>

#define BS 16
#define NP 500000
#define NOBJ 16
#define NSEG3 48        // NOBJ*3
#define GX 128          // blocks per scene, main kernel
#define NSUB 16         // sub-tables per block, selected by lane&15

typedef float f32x4 __attribute__((ext_vector_type(4)));  // native vec for nontemporal store

// ws word layout (all slots written unconditionally every call -> no init pass):
//   slotmin : [0, BS*GX*48)          = [0, 98304)     per-block min keys
//   slotmax : [98304, 196608)                          per-block max keys
//   slotmask: [196608, 198656)        BS*GX            per-block presence bitmask
#define WS_SMAX 98304
#define WS_SMSK 196608

// Order-preserving float -> uint key (min/max over keys == min/max over floats)
__device__ __forceinline__ unsigned fkey(float f) {
    unsigned u = __float_as_uint(f);
    return (u & 0x80000000u) ? ~u : (u | 0x80000000u);
}
__device__ __forceinline__ float keyf(unsigned k) {
    unsigned u = (k & 0x80000000u) ? (k ^ 0x80000000u) : ~k;
    return __uint_as_float(u);
}

// Main fused pass: read pc+tag once; speculative obj_batch = tag + b*16;
// per-block bbox partials via LDS atomics into 16 sub-tables (s = lane&15):
//   idx = (t*3+c)*NSUB + s  -> bank = s + 16*((t+c)&1): ~2 lanes/bank (free),
//   same-address only among 4 lanes sharing s (E[pairs] = C(4,2)/16 = 0.375).
__global__ __launch_bounds__(256) void kmain(const float* __restrict__ pc,
                                             const int* __restrict__ tag,
                                             unsigned* __restrict__ ws,
                                             float* __restrict__ out) {
    __shared__ unsigned lmin[NSUB * NSEG3], lmax[NSUB * NSEG3];
    __shared__ unsigned lmask;
    const int b = blockIdx.y, x = blockIdx.x, tid = threadIdx.x;
    if (tid == 0) lmask = 0u;
    for (int j = tid; j < NSUB * NSEG3; j += 256) { lmin[j] = 0xFFFFFFFFu; lmax[j] = 0u; }
    __syncthreads();

    const int sub = tid & (NSUB - 1);
    const float fb = (float)(b * NOBJ);
    const int4*   tag4 = (const int4*)(tag + (size_t)b * NP);
    const float4* pc4  = (const float4*)(pc + (size_t)b * NP * 3);
    f32x4* out4 = (f32x4*)(out + 2304 + (size_t)b * NP);  // 2304 floats = keypoints
    unsigned m = 0u;
    for (int i = x * 256 + tid; i < NP / 4; i += GX * 256) {
        int4 t = tag4[i];
        float4 f0 = pc4[i * 3 + 0];  // x0 y0 z0 x1
        float4 f1 = pc4[i * 3 + 1];  // y1 z1 x2 y2
        float4 f2 = pc4[i * 3 + 2];  // z2 x3 y3 z3
        f32x4 ob = {fb + (float)t.x, fb + (float)t.y, fb + (float)t.z, fb + (float)t.w};
        __builtin_nontemporal_store(ob, &out4[i]);
        m |= (1u << t.x) | (1u << t.y) | (1u << t.z) | (1u << t.w);
        // idx = (t*3+c)*16 + sub = t*48 + c*16 + sub
        int a0 = t.x * 48 + sub, a1 = t.y * 48 + sub, a2 = t.z * 48 + sub, a3 = t.w * 48 + sub;
        unsigned k;
        k = fkey(f0.x); atomicMin(&lmin[a0 +  0], k); atomicMax(&lmax[a0 +  0], k);
        k = fkey(f0.y); atomicMin(&lmin[a0 + 16], k); atomicMax(&lmax[a0 + 16], k);
        k = fkey(f0.z); atomicMin(&lmin[a0 + 32], k); atomicMax(&lmax[a0 + 32], k);
        k = fkey(f0.w); atomicMin(&lmin[a1 +  0], k); atomicMax(&lmax[a1 +  0], k);
        k = fkey(f1.x); atomicMin(&lmin[a1 + 16], k); atomicMax(&lmax[a1 + 16], k);
        k = fkey(f1.y); atomicMin(&lmin[a1 + 32], k); atomicMax(&lmax[a1 + 32], k);
        k = fkey(f1.z); atomicMin(&lmin[a2 +  0], k); atomicMax(&lmax[a2 +  0], k);
        k = fkey(f1.w); atomicMin(&lmin[a2 + 16], k); atomicMax(&lmax[a2 + 16], k);
        k = fkey(f2.x); atomicMin(&lmin[a2 + 32], k); atomicMax(&lmax[a2 + 32], k);
        k = fkey(f2.y); atomicMin(&lmin[a3 +  0], k); atomicMax(&lmax[a3 +  0], k);
        k = fkey(f2.z); atomicMin(&lmin[a3 + 16], k); atomicMax(&lmax[a3 + 16], k);
        k = fkey(f2.w); atomicMin(&lmin[a3 + 32], k); atomicMax(&lmax[a3 + 32], k);
    }
    atomicOr(&lmask, m);
    __syncthreads();

    const int slot = b * GX + x;
    if (tid < NSEG3) {
        unsigned mn = 0xFFFFFFFFu, mx = 0u;
        #pragma unroll
        for (int s = 0; s < NSUB; ++s) {
            mn = min(mn, lmin[tid * NSUB + s]);
            mx = max(mx, lmax[tid * NSUB + s]);
        }
        ws[slot * NSEG3 + tid] = mn;
        ws[WS_SMAX + slot * NSEG3 + tid] = mx;
    }
    if (tid == 0) ws[WS_SMSK + slot] = lmask;
}

// K3: per-scene reduction of block partials + keypoints epilogue.
// Rare path (some tag absent -> relabel not identity): rewrite scene's obj_batch.
__global__ __launch_bounds__(256) void k3(const unsigned* __restrict__ ws,
                                          float* __restrict__ out) {
    __shared__ unsigned smin[NSEG3], smax[NSEG3];
    __shared__ unsigned smask;
    __shared__ float lut[NOBJ];
    const int b = blockIdx.x, tid = threadIdx.x;

    if (tid < NSEG3) {
        unsigned mn = 0xFFFFFFFFu;
        #pragma unroll 8
        for (int x = 0; x < GX; ++x) mn = min(mn, ws[(b * GX + x) * NSEG3 + tid]);
        smin[tid] = mn;
    } else if (tid >= 64 && tid < 64 + NSEG3) {
        const int e = tid - 64;
        unsigned mx = 0u;
        #pragma unroll 8
        for (int x = 0; x < GX; ++x) mx = max(mx, ws[WS_SMAX + (b * GX + x) * NSEG3 + e]);
        smax[e] = mx;
    } else if (tid == 128) {
        unsigned mm = 0u;
        #pragma unroll 8
        for (int x = 0; x < GX; ++x) mm |= ws[WS_SMSK + b * GX + x];
        smask = mm;
    }
    __syncthreads();
    const unsigned mask = smask;

    if (tid == 0) {
        int tag_of[NOBJ];
        int r = -1;
        for (int t = 0; t < NOBJ; ++t)
            if ((mask >> t) & 1u) { ++r; tag_of[r] = t; }
        int nd = r + 1;
        // bbox rows: [min0, max0, ...] over dense ids; empty dense ids -> 0
        float bbox[32][3];
        for (int i = 0; i < NOBJ; ++i) {
            for (int c = 0; c < 3; ++c) {
                float mn = 0.f, mx = 0.f;
                if (i < nd) {
                    int t = tag_of[i];
                    mn = keyf(smin[t * 3 + c]);
                    mx = keyf(smax[t * 3 + c]);
                }
                bbox[2 * i][c] = mn;
                bbox[2 * i + 1][c] = mx;
            }
        }
        float* ob = out + (size_t)b * 48 * 3;
        for (int j = 0; j < 32; ++j)
            for (int c = 0; c < 3; ++c)
                ob[j * 3 + c] = bbox[j][c];
        // faithful torch barycenter: row-major split of interleaved bbox rows
        for (int j = 0; j < 16; ++j)
            for (int c = 0; c < 3; ++c)
                ob[(32 + j) * 3 + c] = 0.5f * (bbox[j][c] + bbox[16 + j][c]);
    }

    if (mask != 0xFFFFu) {  // rare, input-determined -> deterministic; block-uniform
        if (tid < NOBJ)
            lut[tid] = (float)(__popc(mask & ((2u << tid) - 1u)) - 1 + b * NOBJ);
        __syncthreads();
        const float fb = (float)(b * NOBJ);
        float4* out4 = (float4*)(out + 2304 + (size_t)b * NP);
        for (int i = tid; i < NP / 4; i += 256) {
            float4 v = out4[i];
            out4[i] = make_float4(lut[(int)(v.x - fb)], lut[(int)(v.y - fb)],
                                  lut[(int)(v.z - fb)], lut[(int)(v.w - fb)]);
        }
    }
}

extern "C" void kernel_launch(void* const* d_in, const int* in_sizes, int n_in,
                              void* d_out, int out_size, void* d_ws, size_t ws_size,
                              hipStream_t stream) {
    const float* pc  = (const float*)d_in[0];
    const int*   tag = (const int*)d_in[1];
    float* out = (float*)d_out;
    unsigned* ws = (unsigned*)d_ws;

    kmain<<<dim3(GX, BS), 256, 0, stream>>>(pc, tag, ws, out);
    k3<<<BS, 256, 0, stream>>>(ws, out);
}